// Round 5
// baseline (172.291 us; speedup 1.0000x reference)
//
#include <hip/hip_runtime.h>

// LSTM autoencoder via bf16 MFMA, v13: barrier-free flag sync, two free-running
// batch-half domains in ONE workgroup (768 thr, 12 waves, grid 256, 1 block/CU).
// v8-v12 post-mortem: wall = ~39us VALU/trans issue + ~40us lockstep-barrier idle;
// extra waves (v10) and less LDS traffic (v12) both bought nothing because all
// waves stall at the same program point. Fix: the two batch halves are fully
// independent -> replace all 60 s_barriers with per-wave LDS step-flags so the
// halves drift out of phase and fill each other's SIMD stalls.
//  - producer: h-writes; s_waitcnt lgkmcnt(0); volatile flag[w] = s.
//  - consumer: spin (s_sleep(1)) on needed flags; sched_barrier(0); ds_reads.
//  - phase A: z1@s waits z1>=s-1, z2>=s-2 (dbuf guard); z2@s waits z1>=s, z2>=s-1.
//  - phase B: z4@s waits z3>=s, z4>=s-1; z3@s waits z3>=s-1, z4>=s-2.
//  - roles remapped so each SIMD (w&3 round-robin) hosts BOTH halves:
//    z1 waves 0..7: hf=(w>>2)&1, tile jA=w&3; z2 waves 8..11: hf=w&1, j2=(w>>1)&1.
//  - uniform 30-step loops (step 0 reads zero-initialized buffers); only 2
//    __syncthreads total (init, phase transition).
// Math identical to v11/v12: merged-rcp cellUp (5 exp2 + 2 rcp), pkbf packing,
// log2e folded into weights/biases, z3 input term hoisted.
// aB (stride 264 u16, 32 rows): phA h1 dbuf p*64, h2 dbuf 128+p*32, latent 160..191;
//                               phB h4 dbuf p*64, latent 160, h3 192+p*32.
// LDS: xAll 32x968 (60.5KB) + aB 32x264 (16.5KB) + flags = ~77KB -> 1 block/CU.

#define TT 30
#define FF 16
#define NT 768

typedef unsigned short u16t;
typedef __attribute__((ext_vector_type(8))) short short8;
typedef __attribute__((ext_vector_type(4))) short short4v;
typedef __attribute__((ext_vector_type(4))) float floatx4;

#define MFMA(a, b, c) __builtin_amdgcn_mfma_f32_16x16x32_bf16(a, b, c, 0, 0, 0)

#if __has_builtin(__builtin_amdgcn_exp2f)
#define EXP2(x) __builtin_amdgcn_exp2f(x)
#else
#define EXP2(x) exp2f(x)
#endif

template <int P> struct IC { static constexpr int v = P; };

__device__ __forceinline__ float rcpf(float v) { return __builtin_amdgcn_rcpf(v); }
__device__ __forceinline__ u16t f2bf(float f) {
  unsigned int u = __float_as_uint(f);
  u = (u + 0x7FFFu + ((u >> 16) & 1u)) >> 16;
  return (u16t)u;
}
__device__ __forceinline__ unsigned int pkbf(float a, float b) {
  unsigned int r;
  asm("v_cvt_pk_bf16_f32 %0, %1, %2" : "=v"(r) : "v"(a), "v"(b));
  return r;
}
__device__ __forceinline__ short8 ldFragS(const float* p, float s) {
  const float4 lo = *(const float4*)p;
  const float4 hi = *(const float4*)(p + 4);
  short8 r;
  r[0] = (short)f2bf(lo.x * s); r[1] = (short)f2bf(lo.y * s);
  r[2] = (short)f2bf(lo.z * s); r[3] = (short)f2bf(lo.w * s);
  r[4] = (short)f2bf(hi.x * s); r[5] = (short)f2bf(hi.y * s);
  r[6] = (short)f2bf(hi.z * s); r[7] = (short)f2bf(hi.w * s);
  return r;
}
// Merged-rcp: c = [c(1+ei)(1+eg) + (1-eg)(1+ef)] / [(1+ef)(1+ei)(1+eg)]
__device__ __forceinline__ float cellUp(const floatx4 acc, float& c) {
  float ei = EXP2(-acc[0]);
  float ef = EXP2(-acc[1]);
  float eg = EXP2(-acc[2]);
  float eo = EXP2(-acc[3]);
  float pig = (1.f + ei) * (1.f + eg);
  float pf  = 1.f + ef;
  float num = c * pig + (1.f - eg) * pf;
  c = num * rcpf(pf * pig);
  float ec = EXP2(-2.885390082f * c);
  return (1.f - ec) * rcpf((1.f + eo) * (1.f + ec));       // sig(o)*tanh(c)
}
// Spin until 4 consecutive flags >= tgt (broadcast LDS reads, sleep-backoff).
__device__ __forceinline__ void wait4(const int* f, int tgt) {
  for (;;) {
    int a = *(volatile const int*)&f[0];
    int b = *(volatile const int*)&f[1];
    int c = *(volatile const int*)&f[2];
    int d = *(volatile const int*)&f[3];
    if (a >= tgt && b >= tgt && c >= tgt && d >= tgt) break;
    __builtin_amdgcn_s_sleep(1);
  }
}
__device__ __forceinline__ void wait2(const int* f, int tgt) {
  for (;;) {
    int a = *(volatile const int*)&f[0];
    int b = *(volatile const int*)&f[1];
    if (a >= tgt && b >= tgt) break;
    __builtin_amdgcn_s_sleep(1);
  }
}

__global__ __launch_bounds__(NT, 3) void lstm_ae_mfma13(
    const float* __restrict__ x,
    const float* __restrict__ Wih1, const float* __restrict__ Whh1, const float* __restrict__ b1,
    const float* __restrict__ Wih2, const float* __restrict__ Whh2, const float* __restrict__ b2,
    const float* __restrict__ Wih3, const float* __restrict__ Whh3, const float* __restrict__ b3,
    const float* __restrict__ Wih4, const float* __restrict__ Whh4, const float* __restrict__ b4,
    const float* __restrict__ Wout, const float* __restrict__ bout,
    float* __restrict__ out)
{
  __shared__ __align__(16) u16t xAll[32 * 968];  // x bf16, k16..31 zero-pad, stride 968
  __shared__ __align__(16) u16t aB[32 * 264];    // recurrent state, stride 264
  __shared__ int flg[16];                        // 0..7: z1/z4 (hf*4+jA); 8..11: z2/z3 (8+hf*2+j2)

  const int t = threadIdx.x;
  const int w = t >> 6, lane = t & 63;           // 12 waves
  const int q = lane >> 4, n = lane & 15;
  const int q8 = q * 8;
  const int bBase = blockIdx.x * 32;
  const int nlo = n >> 2, ngt = n & 3;
  const bool isZ1 = (w < 8);
  // SIMD = w&3 (round-robin): mix halves per SIMD.
  const int hf = isZ1 ? ((w >> 2) & 1) : (w & 1);
  const int jA = w & 3;                          // z1/z4 tile group (valid for w<8)
  const int j2 = (w >> 1) & 1;                   // z2/z3 tile group (valid for w>=8)
  const int rh = (n + 16 * hf) * 264;            // this wave's aB row
  const int xh = (n + 16 * hf) * 968;            // this wave's x row
  const int myFlag = isZ1 ? (hf * 4 + jA) : (8 + hf * 2 + j2);

  const float L1 = 1.442695041f, L2 = 2.885390082f;
  const float sA = (ngt == 2) ? L2 : L1;         // gate-g rows scaled 2log2e

  // ================= init =================
  for (int i = t; i < 32 * 264; i += NT) aB[i] = 0;
  for (int i = t; i < 16; i += NT) flg[i] = -1;
  {
    const float* xb = x + (size_t)bBase * (TT * FF);
    for (int i4 = t; i4 < 3840; i4 += NT) {
      int e = i4 * 4;
      int b = e / 480, r = e - b * 480;
      int stp = r >> 4, f = r & 15;
      float4 v = *(const float4*)&xb[e];
      short4v s4 = { (short)f2bf(v.x), (short)f2bf(v.y), (short)f2bf(v.z), (short)f2bf(v.w) };
      *(short4v*)&xAll[b * 968 + stp * 32 + f] = s4;
    }
    for (int i = t; i < 15360; i += NT) {   // zero pads k=16..31
      int b = i / 480, r = i - b * 480;
      int stp = r >> 4, f = r & 15;
      xAll[b * 968 + stp * 32 + 16 + f] = 0;
    }
  }
  const short8 z8 = { 0, 0, 0, 0, 0, 0, 0, 0 };
  short8 wAf[4][3]; floatx4 biasA[4];            // z1 (waves 0..7) or z2 (waves 8..11)
  if (isZ1) {
#pragma unroll
    for (int tt = 0; tt < 4; ++tt) {
      int T = jA + 4 * tt;
      int row = ngt * 64 + T * 4 + nlo;
      wAf[tt][0] = z8;
      if (q < 2) wAf[tt][0] = ldFragS(&Wih1[row * 16 + q8], sA);
      wAf[tt][1] = ldFragS(&Whh1[row * 64 + q8], sA);
      wAf[tt][2] = ldFragS(&Whh1[row * 64 + 32 + q8], sA);
#pragma unroll
      for (int r = 0; r < 4; ++r) biasA[tt][r] = b1[r * 64 + T * 4 + q] * (r == 2 ? L2 : L1);
    }
  } else {
#pragma unroll
    for (int tt = 0; tt < 4; ++tt) {
      int T = j2 + 2 * tt;
      int row = ngt * 32 + T * 4 + nlo;
      wAf[tt][0] = ldFragS(&Wih2[row * 64 + q8], sA);
      wAf[tt][1] = ldFragS(&Wih2[row * 64 + 32 + q8], sA);
      wAf[tt][2] = ldFragS(&Whh2[row * 32 + q8], sA);
#pragma unroll
      for (int r = 0; r < 4; ++r) biasA[tt][r] = b2[r * 32 + T * 4 + q] * (r == 2 ? L2 : L1);
    }
  }
  __syncthreads();

  float cA[4] = {0.f, 0.f, 0.f, 0.f};
  float hv[4];

  // ================= Phase A: uniform 30 steps, flag-synced =================
  auto stepA1 = [&](int s, auto pc) {            // z1@s: h1(s) = f(x(s), h1(s-1))
    constexpr int P = pc.v;                      // P = s&1; read buf 1-P, write buf P
    wait4(&flg[hf * 4], s - 1);
    wait2(&flg[8 + hf * 2], s - 2);
    __builtin_amdgcn_sched_barrier(0);
    const short8 bx  = *(const short8*)&xAll[xh + s * 32 + q8];
    const short8 h1a = *(const short8*)&aB[rh + (1 - P) * 64 + q8];
    const short8 h1b = *(const short8*)&aB[rh + (1 - P) * 64 + 32 + q8];
#pragma unroll
    for (int tt = 0; tt < 4; ++tt) {
      floatx4 a = biasA[tt];
      a = MFMA(wAf[tt][0], bx, a);
      a = MFMA(wAf[tt][1], h1a, a);
      a = MFMA(wAf[tt][2], h1b, a);
      hv[tt] = cellUp(a, cA[tt]);
    }
    unsigned int pk01 = pkbf(hv[0], hv[1]);
    unsigned int pk23 = pkbf(hv[2], hv[3]);
    aB[rh + P * 64 + (jA + 0) * 4 + q] = (u16t)pk01;
    aB[rh + P * 64 + (jA + 4) * 4 + q] = (u16t)(pk01 >> 16);
    aB[rh + P * 64 + (jA + 8) * 4 + q] = (u16t)pk23;
    aB[rh + P * 64 + (jA + 12) * 4 + q] = (u16t)(pk23 >> 16);
    asm volatile("s_waitcnt lgkmcnt(0)" ::: "memory");
    *(volatile int*)&flg[myFlag] = s;
  };
  auto stepA2 = [&](int s, auto pc) {            // z2@s: h2(s) = f(h1(s), h2(s-1))
    constexpr int P = pc.v;
    wait4(&flg[hf * 4], s);
    wait2(&flg[8 + hf * 2], s - 1);
    __builtin_amdgcn_sched_barrier(0);
    const short8 h1a = *(const short8*)&aB[rh + P * 64 + q8];
    const short8 h1b = *(const short8*)&aB[rh + P * 64 + 32 + q8];
    const short8 h2  = *(const short8*)&aB[rh + 128 + (1 - P) * 32 + q8];
#pragma unroll
    for (int tt = 0; tt < 4; ++tt) {
      floatx4 a = biasA[tt];
      a = MFMA(wAf[tt][0], h1a, a);
      a = MFMA(wAf[tt][1], h1b, a);
      a = MFMA(wAf[tt][2], h2, a);
      hv[tt] = cellUp(a, cA[tt]);
    }
    unsigned int pk01 = pkbf(hv[0], hv[1]);
    unsigned int pk23 = pkbf(hv[2], hv[3]);
    const int base = (s == TT - 1) ? (rh + 160) : (rh + 128 + P * 32);  // last step -> latent
    aB[base + (j2 + 0) * 4 + q] = (u16t)pk01;
    aB[base + (j2 + 2) * 4 + q] = (u16t)(pk01 >> 16);
    aB[base + (j2 + 4) * 4 + q] = (u16t)pk23;
    aB[base + (j2 + 6) * 4 + q] = (u16t)(pk23 >> 16);
    asm volatile("s_waitcnt lgkmcnt(0)" ::: "memory");
    *(volatile int*)&flg[myFlag] = s;
  };
  if (isZ1) {
    for (int s = 0; s < TT; s += 2) { stepA1(s, IC<0>{}); stepA1(s + 1, IC<1>{}); }
  } else {
    for (int s = 0; s < TT; s += 2) { stepA2(s, IC<0>{}); stepA2(s + 1, IC<1>{}); }
  }
  __syncthreads();

  // ================= transition: reset flags; zero h4(-1); phase-B weights ====
  for (int i = t; i < 16; i += NT) flg[i] = -1;
  for (int i = t; i < 2048; i += NT) aB[(i >> 6) * 264 + 64 + (i & 63)] = 0;  // h4(-1)=0 (buf1)
  short8 wBf[4][3]; floatx4 biasB[4];
  short8 wof[2]; floatx4 biasO;
  short8 w3h[4]; floatx4 acc3c[4];               // z3: hoisted b3 + Wih3*latent per tile
  if (isZ1) {
#pragma unroll
    for (int tt = 0; tt < 4; ++tt) {
      int T = jA + 4 * tt;
      int row = ngt * 64 + T * 4 + nlo;
      wBf[tt][0] = ldFragS(&Wih4[row * 32 + q8], sA);
      wBf[tt][1] = ldFragS(&Whh4[row * 64 + q8], sA);
      wBf[tt][2] = ldFragS(&Whh4[row * 64 + 32 + q8], sA);
#pragma unroll
      for (int r = 0; r < 4; ++r) biasB[tt][r] = b4[r * 64 + T * 4 + q] * (r == 2 ? L2 : L1);
    }
    wof[0] = ldFragS(&Wout[n * 64 + q8], 1.f);
    wof[1] = ldFragS(&Wout[n * 64 + 32 + q8], 1.f);
    biasO = *(const floatx4*)&bout[q * 4];
  } else {
    const short8 blat = *(const short8*)&aB[rh + 160 + q8];
#pragma unroll
    for (int tt = 0; tt < 4; ++tt) {
      int T = j2 + 2 * tt;
      int row = ngt * 32 + T * 4 + nlo;
      const short8 w3i = ldFragS(&Wih3[row * 32 + q8], sA);
      w3h[tt] = ldFragS(&Whh3[row * 32 + q8], sA);
      floatx4 b3v;
#pragma unroll
      for (int r = 0; r < 4; ++r) b3v[r] = b3[r * 32 + T * 4 + q] * (r == 2 ? L2 : L1);
      acc3c[tt] = MFMA(w3i, blat, b3v);
    }
  }
  __syncthreads();

  float cB[4] = {0.f, 0.f, 0.f, 0.f};

  // ================= Phase B: uniform 30 steps, flag-synced =================
  auto stepB4 = [&](int s, auto pc) {            // z4@s: h4(s) = f(h3(s), h4(s-1)); proj(s-1)
    constexpr int P = pc.v;
    wait2(&flg[8 + hf * 2], s);
    wait4(&flg[hf * 4], s - 1);
    __builtin_amdgcn_sched_barrier(0);
    const short8 h3  = *(const short8*)&aB[rh + 192 + P * 32 + q8];
    const short8 h4a = *(const short8*)&aB[rh + (1 - P) * 64 + q8];
    const short8 h4b = *(const short8*)&aB[rh + (1 - P) * 64 + 32 + q8];
#pragma unroll
    for (int tt = 0; tt < 4; ++tt) {
      floatx4 a = biasB[tt];
      a = MFMA(wBf[tt][0], h3, a);
      a = MFMA(wBf[tt][1], h4a, a);
      a = MFMA(wBf[tt][2], h4b, a);
      hv[tt] = cellUp(a, cB[tt]);
    }
    unsigned int pk01 = pkbf(hv[0], hv[1]);
    unsigned int pk23 = pkbf(hv[2], hv[3]);
    aB[rh + P * 64 + (jA + 0) * 4 + q] = (u16t)pk01;
    aB[rh + P * 64 + (jA + 4) * 4 + q] = (u16t)(pk01 >> 16);
    aB[rh + P * 64 + (jA + 8) * 4 + q] = (u16t)pk23;
    aB[rh + P * 64 + (jA + 12) * 4 + q] = (u16t)(pk23 >> 16);
    asm volatile("s_waitcnt lgkmcnt(0)" ::: "memory");
    *(volatile int*)&flg[myFlag] = s;
    if (s > 0 && jA == ((s - 1) & 3)) {          // proj(s-1) with h4(s-1) in regs; after flag
      floatx4 y = biasO;
      y = MFMA(wof[0], h4a, y);
      y = MFMA(wof[1], h4b, y);
      *(floatx4*)&out[((size_t)(bBase + n + 16 * hf) * TT + (s - 1)) * FF + q * 4] = y;
    }
  };
  auto stepB3 = [&](int s, auto pc) {            // z3@s: h3(s) = f(latent, h3(s-1))
    constexpr int P = pc.v;
    wait2(&flg[8 + hf * 2], s - 1);
    wait4(&flg[hf * 4], s - 2);
    __builtin_amdgcn_sched_barrier(0);
    const short8 h3p = *(const short8*)&aB[rh + 192 + (1 - P) * 32 + q8];
#pragma unroll
    for (int tt = 0; tt < 4; ++tt) {
      floatx4 a = MFMA(w3h[tt], h3p, acc3c[tt]);
      hv[tt] = cellUp(a, cB[tt]);
    }
    unsigned int pk01 = pkbf(hv[0], hv[1]);
    unsigned int pk23 = pkbf(hv[2], hv[3]);
    aB[rh + 192 + P * 32 + (j2 + 0) * 4 + q] = (u16t)pk01;
    aB[rh + 192 + P * 32 + (j2 + 2) * 4 + q] = (u16t)(pk01 >> 16);
    aB[rh + 192 + P * 32 + (j2 + 4) * 4 + q] = (u16t)pk23;
    aB[rh + 192 + P * 32 + (j2 + 6) * 4 + q] = (u16t)(pk23 >> 16);
    asm volatile("s_waitcnt lgkmcnt(0)" ::: "memory");
    *(volatile int*)&flg[myFlag] = s;
  };
  if (isZ1) {
    for (int s = 0; s < TT; s += 2) { stepB4(s, IC<0>{}); stepB4(s + 1, IC<1>{}); }
    if (jA == 1) {                               // proj(29): h4(29) in buf1 (rows 64..127)
      wait4(&flg[hf * 4], TT - 1);
      __builtin_amdgcn_sched_barrier(0);
      const short8 ba = *(const short8*)&aB[rh + 64 + q8];
      const short8 bb = *(const short8*)&aB[rh + 96 + q8];
      floatx4 y = biasO;
      y = MFMA(wof[0], ba, y);
      y = MFMA(wof[1], bb, y);
      *(floatx4*)&out[((size_t)(bBase + n + 16 * hf) * TT + (TT - 1)) * FF + q * 4] = y;
    }
  } else {
    for (int s = 0; s < TT; s += 2) { stepB3(s, IC<0>{}); stepB3(s + 1, IC<1>{}); }
  }
}

extern "C" void kernel_launch(void* const* d_in, const int* in_sizes, int n_in,
                              void* d_out, int out_size, void* d_ws, size_t ws_size,
                              hipStream_t stream) {
  const float* x    = (const float*)d_in[0];
  const float* Wih1 = (const float*)d_in[1];
  const float* Whh1 = (const float*)d_in[2];
  const float* b1   = (const float*)d_in[3];
  const float* Wih2 = (const float*)d_in[4];
  const float* Whh2 = (const float*)d_in[5];
  const float* b2   = (const float*)d_in[6];
  const float* Wih3 = (const float*)d_in[7];
  const float* Whh3 = (const float*)d_in[8];
  const float* b3   = (const float*)d_in[9];
  const float* Wih4 = (const float*)d_in[10];
  const float* Whh4 = (const float*)d_in[11];
  const float* b4   = (const float*)d_in[12];
  const float* Wout = (const float*)d_in[13];
  const float* bout = (const float*)d_in[14];
  float* out = (float*)d_out;

  const int B = in_sizes[0] / (TT * FF);   // 8192
  dim3 grid(B / 32), block(NT);
  lstm_ae_mfma13<<<grid, block, 0, stream>>>(
      x, Wih1, Whh1, b1, Wih2, Whh2, b2, Wih3, Whh3, b3,
      Wih4, Whh4, b4, Wout, bout, out);
}

// Round 6
// 155.200 us; speedup vs baseline: 1.1101x; 1.1101x over previous
//
#include <hip/hip_runtime.h>

// LSTM autoencoder via bf16 MFMA, v14: v11 base (best: 79.9us) + surgical cuts.
// v8-v13 ledger: wall tracks ONLY per-cell issue count (v11 -1 trans -> -3.3us);
// TLP (v10), LDS traffic (v12), sync topology (v13) all neutral-to-negative.
// cellUp trans floor: 5 exp2 + 2 rcp (provably minimal for exact LSTM cell).
// v14 changes vs v11:
//  - x zero-pad merged into the staging loop (separate 15360-iter loop deleted).
//  - rotating proj moved z4-waves -> z3-waves (phase B): z3 issues 4 MFMA/region
//    vs z4's 12; proj on the light wave removes the z4 barrier-straggler skew.
// Geometry: 768 thr, 12 waves, grid 256, 1 block/CU.
// Phase A: waves 0..7: z1 tiles {w,w+8} x2 halves; waves 8..11: z2 x2.
// Phase B: waves 0..7: z4 {w,w+8} x2; waves 8..11: z3 x2 + rotating proj x2.
// log2e folded into weights/biases (gate-g rows x 2log2e); gates exp2(-acc).
// cellUp merged-rcp: 5 exp2 + 2 rcp. pkbf packs tile-pair h conversion.
// barLDS (lgkmcnt-only) in steady state; __syncthreads at phase transitions.
// aB (stride 264 u16, 32 rows): phA h1 dbuf p*64, h2 dbuf 128+p*32, latent 160..191;
//                               phB h4 dbuf p*64, latent 160, h3 192+p*32.
// LDS: xAll 32x968 (60.5KB) + aB 32x264 (16.5KB) = ~77KB -> 1 block/CU.

#define TT 30
#define FF 16
#define NT 768

typedef unsigned short u16t;
typedef __attribute__((ext_vector_type(8))) short short8;
typedef __attribute__((ext_vector_type(4))) short short4v;
typedef __attribute__((ext_vector_type(4))) float floatx4;

#define MFMA(a, b, c) __builtin_amdgcn_mfma_f32_16x16x32_bf16(a, b, c, 0, 0, 0)

#if __has_builtin(__builtin_amdgcn_exp2f)
#define EXP2(x) __builtin_amdgcn_exp2f(x)
#else
#define EXP2(x) exp2f(x)
#endif

template <int P> struct IC { static constexpr int v = P; };

__device__ __forceinline__ float rcpf(float v) { return __builtin_amdgcn_rcpf(v); }
__device__ __forceinline__ u16t f2bf(float f) {
  unsigned int u = __float_as_uint(f);
  u = (u + 0x7FFFu + ((u >> 16) & 1u)) >> 16;
  return (u16t)u;
}
// packed f32x2 -> bf16x2 (RNE), one VALU op
__device__ __forceinline__ unsigned int pkbf(float a, float b) {
  unsigned int r;
  asm("v_cvt_pk_bf16_f32 %0, %1, %2" : "=v"(r) : "v"(a), "v"(b));
  return r;
}
// LDS-only barrier: wait ds ops, skip vmcnt drain (proj global stores don't straggle).
__device__ __forceinline__ void barLDS() {
  asm volatile("s_waitcnt lgkmcnt(0)" ::: "memory");
  __builtin_amdgcn_s_barrier();
}
__device__ __forceinline__ short8 ldFragS(const float* p, float s) {
  const float4 lo = *(const float4*)p;
  const float4 hi = *(const float4*)(p + 4);
  short8 r;
  r[0] = (short)f2bf(lo.x * s); r[1] = (short)f2bf(lo.y * s);
  r[2] = (short)f2bf(lo.z * s); r[3] = (short)f2bf(lo.w * s);
  r[4] = (short)f2bf(hi.x * s); r[5] = (short)f2bf(hi.y * s);
  r[6] = (short)f2bf(hi.z * s); r[7] = (short)f2bf(hi.w * s);
  return r;
}
// acc pre-scaled: [i,f,o] x log2e, [g] x 2log2e. lane owns i,f,g,o of one unit.
// Merged-rcp: c = [c(1+ei)(1+eg) + (1-eg)(1+ef)] / [(1+ef)(1+ei)(1+eg)]
__device__ __forceinline__ float cellUp(const floatx4 acc, float& c) {
  float ei = EXP2(-acc[0]);
  float ef = EXP2(-acc[1]);
  float eg = EXP2(-acc[2]);
  float eo = EXP2(-acc[3]);
  float pig = (1.f + ei) * (1.f + eg);
  float pf  = 1.f + ef;
  float num = c * pig + (1.f - eg) * pf;
  c = num * rcpf(pf * pig);
  float ec = EXP2(-2.885390082f * c);
  return (1.f - ec) * rcpf((1.f + eo) * (1.f + ec));       // sig(o)*tanh(c)
}

__global__ __launch_bounds__(NT, 3) void lstm_ae_mfma14(
    const float* __restrict__ x,
    const float* __restrict__ Wih1, const float* __restrict__ Whh1, const float* __restrict__ b1,
    const float* __restrict__ Wih2, const float* __restrict__ Whh2, const float* __restrict__ b2,
    const float* __restrict__ Wih3, const float* __restrict__ Whh3, const float* __restrict__ b3,
    const float* __restrict__ Wih4, const float* __restrict__ Whh4, const float* __restrict__ b4,
    const float* __restrict__ Wout, const float* __restrict__ bout,
    float* __restrict__ out)
{
  __shared__ __align__(16) u16t xAll[32 * 968];  // x bf16, k16..31 zero-pad, stride 968
  __shared__ __align__(16) u16t aB[32 * 264];    // recurrent state, stride 264

  const int t = threadIdx.x;
  const int w = t >> 6, lane = t & 63;           // 12 waves
  const int q = lane >> 4, n = lane & 15;
  const int q8 = q * 8;
  const int bBase = blockIdx.x * 32;
  const int nlo = n >> 2, ngt = n & 3;
  const int r0 = n * 264, r1 = (n + 16) * 264;   // two batch-half rows
  const int x0 = n * 968, x1 = (n + 16) * 968;
  const bool isZ1 = (w < 8);
  const int u = w & 3;                           // for waves 8..11

  const float L1 = 1.442695041f, L2 = 2.885390082f;
  const float sA = (ngt == 2) ? L2 : L1;         // gate-g rows scaled 2log2e

  // ================= init =================
  for (int i = t; i < 32 * 264; i += NT) aB[i] = 0;
  {
    const float* xb = x + (size_t)bBase * (TT * FF);
    const short4v z4v = { 0, 0, 0, 0 };
    for (int i4 = t; i4 < 3840; i4 += NT) {
      int e = i4 * 4;
      int b = e / 480, r = e - b * 480;
      int stp = r >> 4, f = r & 15;
      float4 v = *(const float4*)&xb[e];
      short4v s4 = { (short)f2bf(v.x), (short)f2bf(v.y), (short)f2bf(v.z), (short)f2bf(v.w) };
      *(short4v*)&xAll[b * 968 + stp * 32 + f] = s4;
      *(short4v*)&xAll[b * 968 + stp * 32 + 16 + f] = z4v;   // merged k16..31 zero-pad
    }
  }
  const short8 z8 = { 0, 0, 0, 0, 0, 0, 0, 0 };
  short8 wAf[2][3]; floatx4 biasA[2];            // z1 (waves 0..7) or z2 (waves 8..11)
  if (isZ1) {
#pragma unroll
    for (int tt = 0; tt < 2; ++tt) {
      int T = w + 8 * tt;
      int row = ngt * 64 + T * 4 + nlo;
      wAf[tt][0] = z8;
      if (q < 2) wAf[tt][0] = ldFragS(&Wih1[row * 16 + q8], sA);
      wAf[tt][1] = ldFragS(&Whh1[row * 64 + q8], sA);
      wAf[tt][2] = ldFragS(&Whh1[row * 64 + 32 + q8], sA);
#pragma unroll
      for (int r = 0; r < 4; ++r) biasA[tt][r] = b1[r * 64 + T * 4 + q] * (r == 2 ? L2 : L1);
    }
  } else {
#pragma unroll
    for (int tt = 0; tt < 2; ++tt) {
      int T = 2 * u + tt;
      int row = ngt * 32 + T * 4 + nlo;
      wAf[tt][0] = ldFragS(&Wih2[row * 64 + q8], sA);
      wAf[tt][1] = ldFragS(&Wih2[row * 64 + 32 + q8], sA);
      wAf[tt][2] = ldFragS(&Whh2[row * 32 + q8], sA);
#pragma unroll
      for (int r = 0; r < 4; ++r) biasA[tt][r] = b2[r * 32 + T * 4 + q] * (r == 2 ? L2 : L1);
    }
  }
  __syncthreads();

  float cA[2][2] = {{0.f, 0.f}, {0.f, 0.f}};     // [half][tile]
  short8 bxN[2];
  float h0v[2], h1v[2];

  // ---- peel: z1(0) (h1(-1)=0) ----
  if (isZ1) {
    const short8 bx0 = *(const short8*)&xAll[x0 + q8];
    const short8 bx1 = *(const short8*)&xAll[x1 + q8];
#pragma unroll
    for (int tt = 0; tt < 2; ++tt) {
      floatx4 a0 = biasA[tt], a1 = biasA[tt];
      a0 = MFMA(wAf[tt][0], bx0, a0);
      a1 = MFMA(wAf[tt][0], bx1, a1);
      h0v[tt] = cellUp(a0, cA[0][tt]);
      h1v[tt] = cellUp(a1, cA[1][tt]);
    }
    unsigned int pk0 = pkbf(h0v[0], h0v[1]);
    unsigned int pk1 = pkbf(h1v[0], h1v[1]);
    aB[r0 + w * 4 + q] = (u16t)pk0;
    aB[r0 + (w + 8) * 4 + q] = (u16t)(pk0 >> 16);
    aB[r1 + w * 4 + q] = (u16t)pk1;
    aB[r1 + (w + 8) * 4 + q] = (u16t)(pk1 >> 16);
    bxN[0] = *(const short8*)&xAll[x0 + 32 + q8];   // prefetch x(1)
    bxN[1] = *(const short8*)&xAll[x1 + 32 + q8];
  }
  barLDS();

  // ================= Phase A: 29 skewed regions, 1 barrier each =================
  auto stepA = [&](int st, auto pc) {
    constexpr int p = decltype(pc)::v;
    const short8 h1a0 = *(const short8*)&aB[r0 + p * 64 + q8];
    const short8 h1b0 = *(const short8*)&aB[r0 + p * 64 + 32 + q8];
    const short8 h1a1 = *(const short8*)&aB[r1 + p * 64 + q8];
    const short8 h1b1 = *(const short8*)&aB[r1 + p * 64 + 32 + q8];
    if (isZ1) {  // z1(st+1) x2 halves
#pragma unroll
      for (int tt = 0; tt < 2; ++tt) {
        floatx4 a0 = biasA[tt], a1 = biasA[tt];
        a0 = MFMA(wAf[tt][0], bxN[0], a0);
        a1 = MFMA(wAf[tt][0], bxN[1], a1);
        a0 = MFMA(wAf[tt][1], h1a0, a0);
        a1 = MFMA(wAf[tt][1], h1a1, a1);
        a0 = MFMA(wAf[tt][2], h1b0, a0);
        a1 = MFMA(wAf[tt][2], h1b1, a1);
        h0v[tt] = cellUp(a0, cA[0][tt]);
        h1v[tt] = cellUp(a1, cA[1][tt]);
      }
      unsigned int pk0 = pkbf(h0v[0], h0v[1]);
      unsigned int pk1 = pkbf(h1v[0], h1v[1]);
      aB[r0 + (1 - p) * 64 + w * 4 + q] = (u16t)pk0;
      aB[r0 + (1 - p) * 64 + (w + 8) * 4 + q] = (u16t)(pk0 >> 16);
      aB[r1 + (1 - p) * 64 + w * 4 + q] = (u16t)pk1;
      aB[r1 + (1 - p) * 64 + (w + 8) * 4 + q] = (u16t)(pk1 >> 16);
      const int nx = (st + 2 < TT) ? st + 2 : TT - 1;
      bxN[0] = *(const short8*)&xAll[x0 + nx * 32 + q8];
      bxN[1] = *(const short8*)&xAll[x1 + nx * 32 + q8];
    } else {     // z2(st) x2 halves
      const short8 h20 = *(const short8*)&aB[r0 + 128 + (1 - p) * 32 + q8];
      const short8 h21 = *(const short8*)&aB[r1 + 128 + (1 - p) * 32 + q8];
#pragma unroll
      for (int tt = 0; tt < 2; ++tt) {
        floatx4 a0 = biasA[tt], a1 = biasA[tt];
        a0 = MFMA(wAf[tt][0], h1a0, a0);
        a1 = MFMA(wAf[tt][0], h1a1, a1);
        a0 = MFMA(wAf[tt][1], h1b0, a0);
        a1 = MFMA(wAf[tt][1], h1b1, a1);
        a0 = MFMA(wAf[tt][2], h20, a0);
        a1 = MFMA(wAf[tt][2], h21, a1);
        h0v[tt] = cellUp(a0, cA[0][tt]);
        h1v[tt] = cellUp(a1, cA[1][tt]);
      }
      unsigned int pk0 = pkbf(h0v[0], h0v[1]);
      unsigned int pk1 = pkbf(h1v[0], h1v[1]);
      aB[r0 + 128 + p * 32 + (2 * u) * 4 + q] = (u16t)pk0;
      aB[r0 + 128 + p * 32 + (2 * u + 1) * 4 + q] = (u16t)(pk0 >> 16);
      aB[r1 + 128 + p * 32 + (2 * u) * 4 + q] = (u16t)pk1;
      aB[r1 + 128 + p * 32 + (2 * u + 1) * 4 + q] = (u16t)(pk1 >> 16);
    }
    barLDS();
  };
  for (int st = 0; st < 28; st += 2) { stepA(st, IC<0>{}); stepA(st + 1, IC<1>{}); }
  stepA(28, IC<0>{});
  // ---- tail: z2(29); h1(29)@64, h2(28)@128 -> latent 160..191 ----
  if (!isZ1) {
    const short8 h1a0 = *(const short8*)&aB[r0 + 64 + q8];
    const short8 h1b0 = *(const short8*)&aB[r0 + 96 + q8];
    const short8 h1a1 = *(const short8*)&aB[r1 + 64 + q8];
    const short8 h1b1 = *(const short8*)&aB[r1 + 96 + q8];
    const short8 h20  = *(const short8*)&aB[r0 + 128 + q8];
    const short8 h21  = *(const short8*)&aB[r1 + 128 + q8];
#pragma unroll
    for (int tt = 0; tt < 2; ++tt) {
      floatx4 a0 = biasA[tt], a1 = biasA[tt];
      a0 = MFMA(wAf[tt][0], h1a0, a0);
      a1 = MFMA(wAf[tt][0], h1a1, a1);
      a0 = MFMA(wAf[tt][1], h1b0, a0);
      a1 = MFMA(wAf[tt][1], h1b1, a1);
      a0 = MFMA(wAf[tt][2], h20, a0);
      a1 = MFMA(wAf[tt][2], h21, a1);
      h0v[tt] = cellUp(a0, cA[0][tt]);
      h1v[tt] = cellUp(a1, cA[1][tt]);
    }
    unsigned int pk0 = pkbf(h0v[0], h0v[1]);
    unsigned int pk1 = pkbf(h1v[0], h1v[1]);
    aB[r0 + 160 + (2 * u) * 4 + q] = (u16t)pk0;
    aB[r0 + 160 + (2 * u + 1) * 4 + q] = (u16t)(pk0 >> 16);
    aB[r1 + 160 + (2 * u) * 4 + q] = (u16t)pk1;
    aB[r1 + 160 + (2 * u + 1) * 4 + q] = (u16t)(pk1 >> 16);
  }
  __syncthreads();

  // ================= transition: phase-B weights; zero h4(-1) =================
  short8 wBf[2][3]; floatx4 biasB[2];
  short8 wof[2]; floatx4 biasO;                  // proj owned by z3 waves now
  short8 w3h[2]; floatx4 acc3c[2][2];            // z3: hoisted b3 + Wih3*latent [tt][half]
  if (isZ1) {
#pragma unroll
    for (int tt = 0; tt < 2; ++tt) {
      int T = w + 8 * tt;
      int row = ngt * 64 + T * 4 + nlo;
      wBf[tt][0] = ldFragS(&Wih4[row * 32 + q8], sA);
      wBf[tt][1] = ldFragS(&Whh4[row * 64 + q8], sA);
      wBf[tt][2] = ldFragS(&Whh4[row * 64 + 32 + q8], sA);
#pragma unroll
      for (int r = 0; r < 4; ++r) biasB[tt][r] = b4[r * 64 + T * 4 + q] * (r == 2 ? L2 : L1);
    }
  } else {
    const short8 blat0 = *(const short8*)&aB[r0 + 160 + q8];
    const short8 blat1 = *(const short8*)&aB[r1 + 160 + q8];
#pragma unroll
    for (int tt = 0; tt < 2; ++tt) {
      int T = 2 * u + tt;
      int row = ngt * 32 + T * 4 + nlo;
      const short8 w3i = ldFragS(&Wih3[row * 32 + q8], sA);
      w3h[tt] = ldFragS(&Whh3[row * 32 + q8], sA);
      floatx4 b3v;
#pragma unroll
      for (int r = 0; r < 4; ++r) b3v[r] = b3[r * 32 + T * 4 + q] * (r == 2 ? L2 : L1);
      acc3c[tt][0] = MFMA(w3i, blat0, b3v);
      acc3c[tt][1] = MFMA(w3i, blat1, b3v);
    }
    wof[0] = ldFragS(&Wout[n * 64 + q8], 1.f);
    wof[1] = ldFragS(&Wout[n * 64 + 32 + q8], 1.f);
    biasO = *(const floatx4*)&bout[q * 4];
  }
  for (int i = t; i < 2048; i += NT) aB[(i >> 6) * 264 + 64 + (i & 63)] = 0;  // h4(-1)=0
  __syncthreads();

  float cB[2][2] = {{0.f, 0.f}, {0.f, 0.f}};

  // ---- peel: z3(0) (h3(-1)=0 -> acc is the hoisted const) ----
  if (!isZ1) {
#pragma unroll
    for (int tt = 0; tt < 2; ++tt) {
      h0v[tt] = cellUp(acc3c[tt][0], cB[0][tt]);
      h1v[tt] = cellUp(acc3c[tt][1], cB[1][tt]);
    }
    unsigned int pk0 = pkbf(h0v[0], h0v[1]);
    unsigned int pk1 = pkbf(h1v[0], h1v[1]);
    aB[r0 + 192 + (2 * u) * 4 + q] = (u16t)pk0;
    aB[r0 + 192 + (2 * u + 1) * 4 + q] = (u16t)(pk0 >> 16);
    aB[r1 + 192 + (2 * u) * 4 + q] = (u16t)pk1;
    aB[r1 + 192 + (2 * u + 1) * 4 + q] = (u16t)(pk1 >> 16);
  }
  barLDS();

  // ================= Phase B: 29 skewed regions, 1 barrier each =================
  auto stepB = [&](int st, auto pc) {
    constexpr int p = decltype(pc)::v;
    const short8 h30 = *(const short8*)&aB[r0 + 192 + p * 32 + q8];
    const short8 h31 = *(const short8*)&aB[r1 + 192 + p * 32 + q8];
    if (isZ1) {  // z4(st) x2 (proj moved to z3 waves)
      const short8 h4a0 = *(const short8*)&aB[r0 + (1 - p) * 64 + q8];
      const short8 h4b0 = *(const short8*)&aB[r0 + (1 - p) * 64 + 32 + q8];
      const short8 h4a1 = *(const short8*)&aB[r1 + (1 - p) * 64 + q8];
      const short8 h4b1 = *(const short8*)&aB[r1 + (1 - p) * 64 + 32 + q8];
#pragma unroll
      for (int tt = 0; tt < 2; ++tt) {
        floatx4 a0 = biasB[tt], a1 = biasB[tt];
        a0 = MFMA(wBf[tt][0], h30, a0);
        a1 = MFMA(wBf[tt][0], h31, a1);
        a0 = MFMA(wBf[tt][1], h4a0, a0);
        a1 = MFMA(wBf[tt][1], h4a1, a1);
        a0 = MFMA(wBf[tt][2], h4b0, a0);
        a1 = MFMA(wBf[tt][2], h4b1, a1);
        h0v[tt] = cellUp(a0, cB[0][tt]);
        h1v[tt] = cellUp(a1, cB[1][tt]);
      }
      unsigned int pk0 = pkbf(h0v[0], h0v[1]);
      unsigned int pk1 = pkbf(h1v[0], h1v[1]);
      aB[r0 + p * 64 + w * 4 + q] = (u16t)pk0;
      aB[r0 + p * 64 + (w + 8) * 4 + q] = (u16t)(pk0 >> 16);
      aB[r1 + p * 64 + w * 4 + q] = (u16t)pk1;
      aB[r1 + p * 64 + (w + 8) * 4 + q] = (u16t)(pk1 >> 16);
    } else {     // z3(st+1) x2 + rotating proj(st-1) x2 (z3 is the light wave)
      if (st > 0 && u == ((st - 1) & 3)) {
        const short8 pa0 = *(const short8*)&aB[r0 + (1 - p) * 64 + q8];
        const short8 pb0 = *(const short8*)&aB[r0 + (1 - p) * 64 + 32 + q8];
        const short8 pa1 = *(const short8*)&aB[r1 + (1 - p) * 64 + q8];
        const short8 pb1 = *(const short8*)&aB[r1 + (1 - p) * 64 + 32 + q8];
        floatx4 y0 = biasO, y1 = biasO;
        y0 = MFMA(wof[0], pa0, y0);
        y1 = MFMA(wof[0], pa1, y1);
        y0 = MFMA(wof[1], pb0, y0);
        y1 = MFMA(wof[1], pb1, y1);
        *(floatx4*)&out[((size_t)(bBase + n) * TT + (st - 1)) * FF + q * 4] = y0;
        *(floatx4*)&out[((size_t)(bBase + n + 16) * TT + (st - 1)) * FF + q * 4] = y1;
      }
#pragma unroll
      for (int tt = 0; tt < 2; ++tt) {
        floatx4 a0 = MFMA(w3h[tt], h30, acc3c[tt][0]);
        floatx4 a1 = MFMA(w3h[tt], h31, acc3c[tt][1]);
        h0v[tt] = cellUp(a0, cB[0][tt]);
        h1v[tt] = cellUp(a1, cB[1][tt]);
      }
      unsigned int pk0 = pkbf(h0v[0], h0v[1]);
      unsigned int pk1 = pkbf(h1v[0], h1v[1]);
      aB[r0 + 192 + (1 - p) * 32 + (2 * u) * 4 + q] = (u16t)pk0;
      aB[r0 + 192 + (1 - p) * 32 + (2 * u + 1) * 4 + q] = (u16t)(pk0 >> 16);
      aB[r1 + 192 + (1 - p) * 32 + (2 * u) * 4 + q] = (u16t)pk1;
      aB[r1 + 192 + (1 - p) * 32 + (2 * u + 1) * 4 + q] = (u16t)(pk1 >> 16);
    }
    barLDS();
  };
  for (int st = 0; st < 28; st += 2) { stepB(st, IC<0>{}); stepB(st + 1, IC<1>{}); }
  stepB(28, IC<0>{});
  // ---- tail: z4(29) (h3(29)@224, h4(28)@buf0); proj(28) by z3-u0; proj(29) by z3-u1 ----
  if (isZ1) {
    const short8 h30  = *(const short8*)&aB[r0 + 224 + q8];
    const short8 h31  = *(const short8*)&aB[r1 + 224 + q8];
    const short8 h4a0 = *(const short8*)&aB[r0 + q8];
    const short8 h4b0 = *(const short8*)&aB[r0 + 32 + q8];
    const short8 h4a1 = *(const short8*)&aB[r1 + q8];
    const short8 h4b1 = *(const short8*)&aB[r1 + 32 + q8];
#pragma unroll
    for (int tt = 0; tt < 2; ++tt) {
      floatx4 a0 = biasB[tt], a1 = biasB[tt];
      a0 = MFMA(wBf[tt][0], h30, a0);
      a1 = MFMA(wBf[tt][0], h31, a1);
      a0 = MFMA(wBf[tt][1], h4a0, a0);
      a1 = MFMA(wBf[tt][1], h4a1, a1);
      a0 = MFMA(wBf[tt][2], h4b0, a0);
      a1 = MFMA(wBf[tt][2], h4b1, a1);
      h0v[tt] = cellUp(a0, cB[0][tt]);
      h1v[tt] = cellUp(a1, cB[1][tt]);
    }
    unsigned int pk0 = pkbf(h0v[0], h0v[1]);
    unsigned int pk1 = pkbf(h1v[0], h1v[1]);
    aB[r0 + 64 + w * 4 + q] = (u16t)pk0;
    aB[r0 + 64 + (w + 8) * 4 + q] = (u16t)(pk0 >> 16);
    aB[r1 + 64 + w * 4 + q] = (u16t)pk1;
    aB[r1 + 64 + (w + 8) * 4 + q] = (u16t)(pk1 >> 16);
  } else if (u == 0) {  // proj(28): h4(28) in buf0 (rows 0..63)
    const short8 pa0 = *(const short8*)&aB[r0 + q8];
    const short8 pb0 = *(const short8*)&aB[r0 + 32 + q8];
    const short8 pa1 = *(const short8*)&aB[r1 + q8];
    const short8 pb1 = *(const short8*)&aB[r1 + 32 + q8];
    floatx4 y0 = biasO, y1 = biasO;
    y0 = MFMA(wof[0], pa0, y0);
    y1 = MFMA(wof[0], pa1, y1);
    y0 = MFMA(wof[1], pb0, y0);
    y1 = MFMA(wof[1], pb1, y1);
    *(floatx4*)&out[((size_t)(bBase + n) * TT + 28) * FF + q * 4] = y0;
    *(floatx4*)&out[((size_t)(bBase + n + 16) * TT + 28) * FF + q * 4] = y1;
  }
  barLDS();
  if (!isZ1 && u == 1) {  // proj(29): h4(29)@64/96
    const short8 ba0 = *(const short8*)&aB[r0 + 64 + q8];
    const short8 bb0 = *(const short8*)&aB[r0 + 96 + q8];
    const short8 ba1 = *(const short8*)&aB[r1 + 64 + q8];
    const short8 bb1 = *(const short8*)&aB[r1 + 96 + q8];
    floatx4 y0 = biasO, y1 = biasO;
    y0 = MFMA(wof[0], ba0, y0);
    y1 = MFMA(wof[0], ba1, y1);
    y0 = MFMA(wof[1], bb0, y0);
    y1 = MFMA(wof[1], bb1, y1);
    *(floatx4*)&out[((size_t)(bBase + n) * TT + 29) * FF + q * 4] = y0;
    *(floatx4*)&out[((size_t)(bBase + n + 16) * TT + 29) * FF + q * 4] = y1;
  }
}

extern "C" void kernel_launch(void* const* d_in, const int* in_sizes, int n_in,
                              void* d_out, int out_size, void* d_ws, size_t ws_size,
                              hipStream_t stream) {
  const float* x    = (const float*)d_in[0];
  const float* Wih1 = (const float*)d_in[1];
  const float* Whh1 = (const float*)d_in[2];
  const float* b1   = (const float*)d_in[3];
  const float* Wih2 = (const float*)d_in[4];
  const float* Whh2 = (const float*)d_in[5];
  const float* b2   = (const float*)d_in[6];
  const float* Wih3 = (const float*)d_in[7];
  const float* Whh3 = (const float*)d_in[8];
  const float* b3   = (const float*)d_in[9];
  const float* Wih4 = (const float*)d_in[10];
  const float* Whh4 = (const float*)d_in[11];
  const float* b4   = (const float*)d_in[12];
  const float* Wout = (const float*)d_in[13];
  const float* bout = (const float*)d_in[14];
  float* out = (float*)d_out;

  const int B = in_sizes[0] / (TT * FF);   // 8192
  dim3 grid(B / 32), block(NT);
  lstm_ae_mfma14<<<grid, block, 0, stream>>>(
      x, Wih1, Whh1, b1, Wih2, Whh2, b2, Wih3, Whh3, b3,
      Wih4, Whh4, b4, Wout, bout, out);
}